// Round 13
// baseline (845.833 us; speedup 1.0000x reference)
//
#include <hip/hip_runtime.h>
#include <hip/hip_bf16.h>

#define NN 50000
#define EE 800000
#define GG 64
#define RR 3
#define METAD 38
#define NSEG (RR*NN)
#define EPSV 1e-5f

typedef __bf16 bf_t;
typedef __attribute__((ext_vector_type(8))) __bf16 bf16x8;
typedef __attribute__((ext_vector_type(4))) __bf16 bf16x4;
typedef __attribute__((ext_vector_type(2))) __bf16 bf16x2;
typedef __attribute__((ext_vector_type(4))) float f32x4;
typedef __attribute__((address_space(1))) void gas_t;
typedef __attribute__((address_space(3))) void las_t;

__device__ __forceinline__ float loadf(const void* p, size_t i, int flag){
  return flag ? ((const float*)p)[i] : (float)(((const bf_t*)p)[i]);
}

// ---------------- dtype detector: fp32 (1) vs bf16 (0) ----------------
__global__ __launch_bounds__(256) void detect_kernel(const void* __restrict__ xraw,
                                                     int* __restrict__ flag){
  __shared__ int found;
  if (threadIdx.x == 0) found = 0;
  __syncthreads();
  const unsigned short* u = (const unsigned short*)xraw;
  for (int i = threadIdx.x; i < 65536; i += 256){
    int e = (u[i] >> 7) & 0xFF;
    if (e >= 0xF0) found = 1;
  }
  __syncthreads();
  if (threadIdx.x == 0) *flag = found;
}

// ---------------- merged small-param convert ----------------
struct CvtJobs {
  const void* src[17];
  float* dst[17];
  int n[17];
};

__global__ __launch_bounds__(256) void cvt_many(CvtJobs j, const int* __restrict__ flag){
  int job = blockIdx.y;
  int i = blockIdx.x*256 + threadIdx.x;
  if (i < j.n[job]) j.dst[job][i] = loadf(j.src[job], i, *flag);
}

// ---------------- pack weights: WbT[o][r*DP+i] = W[r][i][o] (bf16, zero-padded) ----------------
__global__ __launch_bounds__(256) void pack_w(const void* __restrict__ W,
                                              const void* __restrict__ R,
                                              bf_t* __restrict__ out,
                                              int D, int O, int dplog,
                                              const int* __restrict__ flag){
  int id = blockIdx.x*256 + threadIdx.x;
  int DP4 = 1 << (dplog + 2);
  int o = id >> (dplog + 2);
  int k = id & (DP4 - 1);
  int r = k >> dplog;
  int i = k & ((1 << dplog) - 1);
  float v = 0.f;
  int fl = *flag;
  if (i < D && o < O){
    if (r < 3) v = loadf(W, ((size_t)r*D + i)*O + o, fl);
    else       v = loadf(R, (size_t)i*O + o, fl);
  }
  out[(size_t)o*DP4 + k] = (bf_t)v;
}

// ---------------- CSR build ----------------
__global__ __launch_bounds__(256) void counti_kernel(const int* __restrict__ ei,
                                                     const int* __restrict__ et,
                                                     int* __restrict__ cnt){
  int e = blockIdx.x*256 + threadIdx.x;
  if (e < EE) atomicAdd(&cnt[et[e]*NN + ei[EE + e]], 1);
}

__global__ __launch_bounds__(256) void rcnt_kernel(const int* __restrict__ cnt,
                                                   float* __restrict__ rcnt){
  int i = blockIdx.x*256 + threadIdx.x;
  if (i < NSEG) rcnt[i] = 1.0f / (float)max(cnt[i], 1);
}

__global__ __launch_bounds__(256) void scan1_kernel(const int* __restrict__ cnt,
                                                    int* __restrict__ segoff,
                                                    int* __restrict__ bsums){
  __shared__ int sh[256];
  int i = blockIdx.x*256 + threadIdx.x;
  int v = (i < NSEG) ? cnt[i] : 0;
  sh[threadIdx.x] = v;
  __syncthreads();
  for (int off = 1; off < 256; off <<= 1){
    int t = 0;
    if (threadIdx.x >= off) t = sh[threadIdx.x - off];
    __syncthreads();
    if (threadIdx.x >= off) sh[threadIdx.x] += t;
    __syncthreads();
  }
  if (i < NSEG) segoff[i] = sh[threadIdx.x] - v;
  if (threadIdx.x == 255) bsums[blockIdx.x] = sh[255];
}

__global__ __launch_bounds__(256) void scan2_kernel(int* __restrict__ bsums, int nb){
  __shared__ int sh[256];
  __shared__ int carry;
  if (threadIdx.x == 0) carry = 0;
  __syncthreads();
  for (int base = 0; base < nb; base += 256){
    int i = base + threadIdx.x;
    int v = (i < nb) ? bsums[i] : 0;
    sh[threadIdx.x] = v;
    __syncthreads();
    for (int off = 1; off < 256; off <<= 1){
      int t = 0;
      if (threadIdx.x >= off) t = sh[threadIdx.x - off];
      __syncthreads();
      if (threadIdx.x >= off) sh[threadIdx.x] += t;
      __syncthreads();
    }
    if (i < nb) bsums[i] = sh[threadIdx.x] - v + carry;
    __syncthreads();
    if (threadIdx.x == 0) carry += sh[255];
    __syncthreads();
  }
}

__global__ __launch_bounds__(256) void scan3_kernel(int* __restrict__ segoff,
                                                    const int* __restrict__ bsums){
  int i = blockIdx.x*256 + threadIdx.x;
  if (i < NSEG) segoff[i] += bsums[blockIdx.x];
  if (i == 0) segoff[NSEG] = EE;
}

__global__ __launch_bounds__(256) void curinit_kernel(const int* __restrict__ segoff,
                                                      int* __restrict__ cursor){
  int i = blockIdx.x*256 + threadIdx.x;
  if (i < NSEG) cursor[i] = segoff[i];
}

__global__ __launch_bounds__(256) void place_kernel(const int* __restrict__ ei,
                                                    const int* __restrict__ et,
                                                    int* __restrict__ cursor,
                                                    int* __restrict__ srcs){
  int e = blockIdx.x*256 + threadIdx.x;
  if (e < EE){
    int seg = et[e]*NN + ei[EE + e];
    int pos = atomicAdd(&cursor[seg], 1);
    srcs[pos] = ei[e];
  }
}

// ---------------- x -> Ab slice3 (layer0, D=DP=128, lda=512) ----------------
__global__ __launch_bounds__(128) void cvt_x(const void* __restrict__ x,
                                             bf_t* __restrict__ Ab,
                                             const int* __restrict__ flag){
  int d = blockIdx.x, t = threadIdx.x;
  Ab[(size_t)d*512 + 384 + t] = (bf_t)loadf(x, (size_t)d*128 + t, *flag);
}

// ------- wave-per-segment CSR gather mean: exact 4-wide + ONE predicated tail trip -------
// R19-verified (845us e2e, aggregate left the top-5).  FROZEN.
template<int DP>
__global__ __launch_bounds__(256) void aggregate_wave(const bf_t* __restrict__ Ab, int lda,
                                                      const int* __restrict__ segoff,
                                                      const int* __restrict__ srcs,
                                                      const float* __restrict__ rcnt,
                                                      const bf_t* __restrict__ zrow,
                                                      bf_t* __restrict__ out){
  int wid = (blockIdx.x*256 + threadIdx.x) >> 6;
  if (wid >= NSEG) return;
  wid = __builtin_amdgcn_readfirstlane(wid);   // wave-uniform -> SGPR chain
  int lane = threadIdx.x & 63;
  int r = wid / NN;
  int d = wid - r*NN;
  int s0 = segoff[wid], s1 = segoff[wid + 1];
  float rc = rcnt[wid];
  const bf_t* in = Ab + 3*DP;

  if (DP == 256){
    float a0=0.f, a1=0.f, a2=0.f, a3=0.f;
    const int off = lane*4;
    const bf_t* zp = zrow + off;
    int e = s0;
    for (; e + 4 <= s1; e += 4){
      int sA = srcs[e], sB = srcs[e+1], sC = srcs[e+2], sD = srcs[e+3];
      uint2 vA = *(const uint2*)(in + (size_t)sA*lda + off);
      uint2 vB = *(const uint2*)(in + (size_t)sB*lda + off);
      uint2 vC = *(const uint2*)(in + (size_t)sC*lda + off);
      uint2 vD = *(const uint2*)(in + (size_t)sD*lda + off);
      a0 += __uint_as_float(vA.x << 16); a1 += __uint_as_float(vA.x & 0xFFFF0000u);
      a2 += __uint_as_float(vA.y << 16); a3 += __uint_as_float(vA.y & 0xFFFF0000u);
      a0 += __uint_as_float(vB.x << 16); a1 += __uint_as_float(vB.x & 0xFFFF0000u);
      a2 += __uint_as_float(vB.y << 16); a3 += __uint_as_float(vB.y & 0xFFFF0000u);
      a0 += __uint_as_float(vC.x << 16); a1 += __uint_as_float(vC.x & 0xFFFF0000u);
      a2 += __uint_as_float(vC.y << 16); a3 += __uint_as_float(vC.y & 0xFFFF0000u);
      a0 += __uint_as_float(vD.x << 16); a1 += __uint_as_float(vD.x & 0xFFFF0000u);
      a2 += __uint_as_float(vD.y << 16); a3 += __uint_as_float(vD.y & 0xFFFF0000u);
    }
    if (e < s1){                        // single predicated trip, <=3 loads, all independent
      int sA = srcs[e];
      int sB = srcs[min(e+1, s1-1)];
      int sC = srcs[min(e+2, s1-1)];
      const uint2* pA = (const uint2*)(in + (size_t)sA*lda + off);
      const uint2* pB = (e+1 < s1) ? (const uint2*)(in + (size_t)sB*lda + off) : (const uint2*)zp;
      const uint2* pC = (e+2 < s1) ? (const uint2*)(in + (size_t)sC*lda + off) : (const uint2*)zp;
      uint2 vA = *pA, vB = *pB, vC = *pC;
      a0 += __uint_as_float(vA.x << 16); a1 += __uint_as_float(vA.x & 0xFFFF0000u);
      a2 += __uint_as_float(vA.y << 16); a3 += __uint_as_float(vA.y & 0xFFFF0000u);
      a0 += __uint_as_float(vB.x << 16); a1 += __uint_as_float(vB.x & 0xFFFF0000u);
      a2 += __uint_as_float(vB.y << 16); a3 += __uint_as_float(vB.y & 0xFFFF0000u);
      a0 += __uint_as_float(vC.x << 16); a1 += __uint_as_float(vC.x & 0xFFFF0000u);
      a2 += __uint_as_float(vC.y << 16); a3 += __uint_as_float(vC.y & 0xFFFF0000u);
    }
    bf16x4 o = {(bf_t)(a0*rc), (bf_t)(a1*rc), (bf_t)(a2*rc), (bf_t)(a3*rc)};
    *(bf16x4*)(out + (size_t)d*lda + r*DP + off) = o;
  } else {
    float a0=0.f, a1=0.f;
    const int off = lane*2;
    const bf_t* zp = zrow + off;
    int e = s0;
    for (; e + 4 <= s1; e += 4){
      int sA = srcs[e], sB = srcs[e+1], sC = srcs[e+2], sD = srcs[e+3];
      unsigned vA = *(const unsigned*)(in + (size_t)sA*lda + off);
      unsigned vB = *(const unsigned*)(in + (size_t)sB*lda + off);
      unsigned vC = *(const unsigned*)(in + (size_t)sC*lda + off);
      unsigned vD = *(const unsigned*)(in + (size_t)sD*lda + off);
      a0 += __uint_as_float(vA << 16); a1 += __uint_as_float(vA & 0xFFFF0000u);
      a0 += __uint_as_float(vB << 16); a1 += __uint_as_float(vB & 0xFFFF0000u);
      a0 += __uint_as_float(vC << 16); a1 += __uint_as_float(vC & 0xFFFF0000u);
      a0 += __uint_as_float(vD << 16); a1 += __uint_as_float(vD & 0xFFFF0000u);
    }
    if (e < s1){
      int sA = srcs[e];
      int sB = srcs[min(e+1, s1-1)];
      int sC = srcs[min(e+2, s1-1)];
      const unsigned* pA = (const unsigned*)(in + (size_t)sA*lda + off);
      const unsigned* pB = (e+1 < s1) ? (const unsigned*)(in + (size_t)sB*lda + off) : (const unsigned*)zp;
      const unsigned* pC = (e+2 < s1) ? (const unsigned*)(in + (size_t)sC*lda + off) : (const unsigned*)zp;
      unsigned vA = *pA, vB = *pB, vC = *pC;
      a0 += __uint_as_float(vA << 16); a1 += __uint_as_float(vA & 0xFFFF0000u);
      a0 += __uint_as_float(vB << 16); a1 += __uint_as_float(vB & 0xFFFF0000u);
      a0 += __uint_as_float(vC << 16); a1 += __uint_as_float(vC & 0xFFFF0000u);
    }
    bf16x2 o = {(bf_t)(a0*rc), (bf_t)(a1*rc)};
    *(bf16x2*)(out + (size_t)d*lda + r*DP + off) = o;
  }
}

// ------- MFMA GEMM: 256x256 tile, 16 waves x (64x64), BK=32, dbuf, counted vmcnt, bf16 C -------
// R27 evidence: ALL seven 128x128-tile variants land at 65-72us because they
// share the invariant: 782 blocks x 512KB panels = 400MB of global_load_lds
// staging traffic (L2+HBM mix) at ~6.2 TB/s = the stream ceiling.  bf16-C
// (R12: write 50.8->25.8MB) moved dur only 65.8->65.0 -> not write-bound.
// Fix = REUSE: 256x256 tile -> 196 blocks, staged bytes HALVE to 196MB
// (K=1024).  1024 threads / 16 waves, per-wave 64x64 out (8 ds_reads : 16
// MFMAs).  Staging = exactly 1 A + 1 B load per thread per tile (wave w owns
// 16 rows; dest wave-uniform base + lane*16).  vmcnt(2) counted, 2 tiles in
// flight, never 0 in-loop.  R23's HW-proven zero-conflict involution verbatim
// (staging kchunk (lane&3)^((lane>>3)&3); read slot quad^((l15>>1)&3)).
// LDS 64KB dbuf + 2KB colsum; __launch_bounds__(1024,4) caps VGPR at 128.
#define ISSUE2(B_, KO_)                                                                             \
  { uint4* _b = &lds4[B_][0];                                                                       \
    __builtin_amdgcn_global_load_lds((gas_t*)(ArG + (KO_)), (las_t*)(_b + wave*64), 16, 0, 0);      \
    __builtin_amdgcn_global_load_lds((gas_t*)(BrG + (KO_)), (las_t*)(_b + 1024 + wave*64), 16, 0, 0); }

template<int NT>
__global__ __launch_bounds__(1024, 4) void gemm_mfma2(const bf_t* __restrict__ A, int lda, int K,
                                                      const bf_t* __restrict__ Bt,
                                                      const float* __restrict__ bias,
                                                      bf_t* __restrict__ C, int ldc, int O,
                                                      float* __restrict__ sums){
  __shared__ uint4 lds4[2][2048];        // per buf: A 16KB (0..1023) + B 16KB (1024..2047)
  __shared__ float colsum[2*NT];         // 512 floats
  float* stage = (float*)lds4;           // epilogue overlay: 32 rows x 260 floats = 33280B

  int tid = threadIdx.x;
  int lane = tid & 63;
  int wave = tid >> 6;                   // 0..15
  int wr = wave & 3, wc = wave >> 2;     // 4x4 grid of 64x64 wave tiles
  int row0 = blockIdx.x*256;
  int col0 = 0;
  int l15 = lane & 15, quad = lane >> 4;
  f32x4 acc[4][4] = {};

  // staging: wave w owns local rows [w*16, w*16+16); lane -> row w*16+(lane>>2),
  // LDS slot lane&3 (linear dest = wave base + lane*16).  Source kchunk
  // PRE-SWIZZLED: slot s of local row lr holds global kchunk s^((lr>>1)&3)
  // (== s^((lane>>3)&3) since w*16 is a multiple of 8).
  int skc8 = ((lane & 3) ^ ((lane >> 3) & 3)) * 8;
  int arow = row0 + wave*16 + (lane >> 2); if (arow >= NN) arow = NN - 1;
  const bf_t* ArG = A + (size_t)arow*lda + skc8;
  const bf_t* BrG = Bt + (size_t)(col0 + wave*16 + (lane >> 2))*K + skc8;

  int niter = K >> 5;
  ISSUE2(0, 0)
  ISSUE2(1, 32)

  int sx = (l15 >> 1) & 3;               // read-side of the involution
  for (int i = 0; i < niter; ++i){
    if (i + 1 < niter) asm volatile("s_waitcnt vmcnt(2)" ::: "memory");
    else               asm volatile("s_waitcnt vmcnt(0)" ::: "memory");
    __builtin_amdgcn_s_barrier();
    asm volatile("" ::: "memory");
    __builtin_amdgcn_sched_barrier(0);

    const uint4* As4 = &lds4[i & 1][0];
    const uint4* Bs4 = As4 + 1024;
    bf16x8 af[4], bfv[4];
    #pragma unroll
    for (int mi = 0; mi < 4; ++mi){
      int R = wr*64 + mi*16 + l15;
      af[mi] = *(const bf16x8*)&As4[R*4 + (quad ^ sx)];
    }
    #pragma unroll
    for (int ni = 0; ni < 4; ++ni){
      int Rb = wc*64 + ni*16 + l15;
      bfv[ni] = *(const bf16x8*)&Bs4[Rb*4 + (quad ^ sx)];
    }
    #pragma unroll
    for (int mi = 0; mi < 4; ++mi)
      #pragma unroll
      for (int ni = 0; ni < 4; ++ni)
        acc[mi][ni] = __builtin_amdgcn_mfma_f32_16x16x32_bf16(af[mi], bfv[ni], acc[mi][ni], 0, 0, 0);

    asm volatile("s_waitcnt lgkmcnt(0)" ::: "memory");
    __builtin_amdgcn_s_barrier();
    if (i + 2 < niter) ISSUE2(i & 1, (i + 2) << 5)
  }

  // ---- epilogue: BN partials + staged coalesced bf16 C store (16-wave 64x64 layout) ----
  __syncthreads();
  if (tid < 2*NT) colsum[tid] = 0.f;
  float bzv[4];
  #pragma unroll
  for (int ni = 0; ni < 4; ++ni){
    int col = col0 + wc*64 + ni*16 + l15;
    bzv[ni] = (col < O) ? bias[col] : 0.f;
  }
  __syncthreads();

  #pragma unroll
  for (int ni = 0; ni < 4; ++ni){
    int lcol = wc*64 + ni*16 + l15;
    int col = col0 + lcol;
    if (col < O){
      float scol = 0.f, qcol = 0.f;
      #pragma unroll
      for (int mi = 0; mi < 4; ++mi){
        int rbase = row0 + wr*64 + mi*16 + quad*4;
        #pragma unroll
        for (int j = 0; j < 4; ++j){
          if (rbase + j < NN){
            float v = acc[mi][ni][j] + bzv[ni];
            scol += v; qcol += v*v;
          }
        }
      }
      atomicAdd(&colsum[lcol], scol);
      atomicAdd(&colsum[NT + lcol], qcol);
    }
  }

  constexpr int STR = NT + 4;            // 260 floats
  int rl0 = tid >> 5;                    // 0..31 (32 threads per row)
  int cg = (tid & 31)*8;                 // 8 cols per thread
  #pragma unroll
  for (int c = 0; c < 8; ++c){           // row chunks of 32
    __syncthreads();
    if (wr == (c >> 1)){
      int base = (c & 1)*32;
      #pragma unroll
      for (int m2 = 0; m2 < 2; ++m2){
        int mi = (c & 1)*2 + m2;
        #pragma unroll
        for (int ni = 0; ni < 4; ++ni)
          #pragma unroll
          for (int j = 0; j < 4; ++j)
            stage[(mi*16 + quad*4 + j - base)*STR + wc*64 + ni*16 + l15] = acc[mi][ni][j] + bzv[ni];
      }
    }
    __syncthreads();
    int gr = row0 + c*32 + rl0;
    if (gr < NN && cg < ldc){
      const float* sp = &stage[rl0*STR + cg];
      bf16x8 o = {(bf_t)sp[0], (bf_t)sp[1], (bf_t)sp[2], (bf_t)sp[3],
                  (bf_t)sp[4], (bf_t)sp[5], (bf_t)sp[6], (bf_t)sp[7]};
      *(bf16x8*)&C[(size_t)gr*ldc + col0 + cg] = o;
    }
  }

  __syncthreads();
  for (int c = tid; c < NT; c += 1024){
    int col = col0 + c;
    if (col < O){
      unsafeAtomicAdd(&sums[col], colsum[c]);
      unsafeAtomicAdd(&sums[256 + col], colsum[NT + c]);
    }
  }
}

// ---------------- BN finalize ----------------
__global__ __launch_bounds__(256) void bn_finalize(const float* __restrict__ sums,
                                                   const float* __restrict__ g,
                                                   const float* __restrict__ bb,
                                                   float* __restrict__ scale,
                                                   float* __restrict__ shift, int dout){
  int c = threadIdx.x;
  if (c < dout){
    float mu = sums[c] * (1.0f/NN);
    float var = sums[256 + c] * (1.0f/NN) - mu*mu;
    float rstd = rsqrtf(fmaxf(var, 0.f) + EPSV);
    float s = rstd * g[c];
    scale[c] = s;
    shift[c] = bb[c] - mu*s;
  }
}

// BN apply fused with bf16 convert into Ab slice3 (bf16 C input)
template<int DPN>
__global__ __launch_bounds__(DPN) void bn_cvt(const bf_t* __restrict__ C, int ldc, int O,
                                              const float* __restrict__ scale,
                                              const float* __restrict__ shift,
                                              bf_t* __restrict__ Ab, int ldan){
  int d = blockIdx.x, t = threadIdx.x;
  float v = 0.f;
  if (t < O) v = (float)C[(size_t)d*ldc + t]*scale[t] + shift[t];
  Ab[(size_t)d*ldan + 3*DPN + t] = (bf_t)v;
}

// ---------------- global mean pool (batch sorted, bf16 input from Ab slice3) ----------------
__device__ __forceinline__ int lower_bound(const int* __restrict__ a, int v){
  int lo = 0, hi = NN;
  while (lo < hi){ int m = (lo+hi) >> 1; if (a[m] < v) lo = m+1; else hi = m; }
  return lo;
}

__global__ __launch_bounds__(256) void pool_kernel(const bf_t* __restrict__ H,
                                                   const int* __restrict__ batch,
                                                   float* __restrict__ pooled){
  int g = blockIdx.x, sl = blockIdx.y;
  int start = lower_bound(batch, g), end = lower_bound(batch, g+1);
  int len = end - start;
  float inv = 1.0f / (float)max(len, 1);
  int chunk = (len + 7) >> 3;
  int s0 = start + sl*chunk;
  int s1 = min(s0 + chunk, end);
  float s = 0.f;
  for (int n = s0; n < s1; ++n) s += (float)H[(size_t)n*1024 + threadIdx.x];
  if (s1 > s0) unsafeAtomicAdd(&pooled[g*256 + threadIdx.x], s * inv);
}

// ---------------- final MLP ----------------
__global__ __launch_bounds__(128) void final_kernel(const float* __restrict__ pooled,
                                                    const float* __restrict__ meta,
                                                    const float* __restrict__ w1,
                                                    const float* __restrict__ b1,
                                                    const float* __restrict__ w2,
                                                    const float* __restrict__ b2,
                                                    void* __restrict__ out,
                                                    const int* __restrict__ flag){
  int g = blockIdx.x;
  __shared__ float h1[100];
  __shared__ float red[128];
  int t = threadIdx.x;
  if (t < 100){
    float acc = b1[t];
    for (int k = 0; k < 256; ++k) acc += pooled[g*256 + k] * w1[k*100 + t];
    for (int k = 0; k < METAD; ++k) acc += meta[g*METAD + k] * w1[(256+k)*100 + t];
    h1[t] = acc;
  }
  __syncthreads();
  red[t] = (t < 100) ? h1[t] * w2[t] : 0.f;
  __syncthreads();
  for (int s = 64; s > 0; s >>= 1){
    if (t < s) red[t] += red[t + s];
    __syncthreads();
  }
  if (t == 0){
    float v = red[0] + b2[0];
    if (*flag) ((float*)out)[g] = v;
    else       ((__hip_bfloat16*)out)[g] = __float2bfloat16(v);
  }
}

// ---------------- launch ----------------
extern "C" void kernel_launch(void* const* d_in, const int* in_sizes, int n_in,
                              void* d_out, int out_size, void* d_ws, size_t ws_size,
                              hipStream_t stream){
  const void* x    = d_in[0];
  const int*  ei   = (const int*)d_in[2];
  const int*  et   = (const int*)d_in[3];
  const int*  batch= (const int*)d_in[5];

  // ---- workspace layout (float units) ----
  float* ws     = (float*)d_ws;
  int*   flag   = (int*)ws;                    // 16
  float* rcnt   = ws + 16;                     // 150000 -> 150016
  int*   cnt    = (int*)(ws + 150016);         // -> (pad 300032)
  int*   segoff = (int*)(ws + 300032);         // 150001 -> (pad 450048)
  int*   bsums  = (int*)(ws + 450048);         // 1024 -> 451072 (dead after scan3 -> zero row)
  int*   srcs   = (int*)(ws + 451072);         // 800000 -> 1251072
  float* sums   = ws + 1251072;                // 512 -> 1251584
  float* scale  = ws + 1251584;                // 256
  float* shift  = ws + 1251840;                // 256
  float* pooled = ws + 1252096;                // 16384 -> 1268480
  float* bc     = ws + 1268480;                // 868
  float* gc_    = ws + 1269348;                // 868
  float* bbc    = ws + 1270216;                // 868
  float* metaf  = ws + 1271084;                // 2432
  float* w1f    = ws + 1273516;                // 29400
  float* b1f    = ws + 1302916;                // 100
  float* w2f    = ws + 1303016;                // 100
  float* b2f_   = ws + 1303116;                // 1 (pad 1303168)
  bf_t*  wt     = (bf_t*)(ws + 1303168);       // 720896 bf16 -> 1663616
  int*   cursor = (int*)(ws + 1663616);        // 150000 -> (pad 1813632)
  bf_t*  C      = (bf_t*)(ws + 1813632);       // 12.8M bf16 (25.6MB)
  bf_t*  Ab     = (bf_t*)(ws + 14613632);      // 51200000 bf16 -> 40213632 (160.9 MB)

  const size_t wtoff[4] = {0, 65536, 196608, 458752};

  detect_kernel<<<1, 256, 0, stream>>>(x, flag);

  // ---- merged small-param convert (17 jobs, one launch) ----
  const int vsz[4]  = {100, 256, 256, 256};
  const int voff[4] = {0, 100, 356, 612};
  float *bfp[4], *gf[4], *bbf[4];
  CvtJobs J;
  int nj = 0;
  for (int l = 0; l < 4; ++l){
    bfp[l] = bc + voff[l]; gf[l] = gc_ + voff[l]; bbf[l] = bbc + voff[l];
    J.src[nj] = d_in[6 + l*5 + 2]; J.dst[nj] = bfp[l]; J.n[nj] = vsz[l]; nj++;
    J.src[nj] = d_in[6 + l*5 + 3]; J.dst[nj] = gf[l];  J.n[nj] = vsz[l]; nj++;
    J.src[nj] = d_in[6 + l*5 + 4]; J.dst[nj] = bbf[l]; J.n[nj] = vsz[l]; nj++;
  }
  J.src[nj] = d_in[4];  J.dst[nj] = metaf; J.n[nj] = GG*METAD; nj++;
  J.src[nj] = d_in[26]; J.dst[nj] = w1f;   J.n[nj] = 29400; nj++;
  J.src[nj] = d_in[27]; J.dst[nj] = b1f;   J.n[nj] = 100; nj++;
  J.src[nj] = d_in[28]; J.dst[nj] = w2f;   J.n[nj] = 100; nj++;
  J.src[nj] = d_in[29]; J.dst[nj] = b2f_;  J.n[nj] = 1; nj++;
  cvt_many<<<dim3(115, nj), 256, 0, stream>>>(J, flag);

  // ---- pack weights to bf16 [Op][4*DP] ----
  const int din[4] = {128, 100, 256, 256};
  const int dou[4] = {100, 256, 256, 256};
  const int DP[4]  = {128, 128, 256, 256};
  const int dplog[4] = {7, 7, 8, 8};
  const int Op[4]  = {128, 256, 256, 256};
  for (int l = 0; l < 4; ++l){
    int total = Op[l] << (dplog[l] + 2);
    pack_w<<<total/256, 256, 0, stream>>>(d_in[6 + l*5 + 0], d_in[6 + l*5 + 1],
                                          wt + wtoff[l], din[l], dou[l], dplog[l], flag);
  }

  // ---- CSR build ----
  hipMemsetAsync(cnt, 0, NSEG*sizeof(int), stream);
  counti_kernel<<<(EE+255)/256, 256, 0, stream>>>(ei, et, cnt);
  rcnt_kernel<<<(NSEG+255)/256, 256, 0, stream>>>(cnt, rcnt);
  int nb = (NSEG + 255)/256;
  scan1_kernel<<<nb, 256, 0, stream>>>(cnt, segoff, bsums);
  scan2_kernel<<<1, 256, 0, stream>>>(bsums, nb);
  scan3_kernel<<<nb, 256, 0, stream>>>(segoff, bsums);
  curinit_kernel<<<nb, 256, 0, stream>>>(segoff, cursor);
  place_kernel<<<(EE+255)/256, 256, 0, stream>>>(ei, et, cursor, srcs);
  // bsums is dead now -> becomes the 512B zero row for predicated gathers
  hipMemsetAsync(bsums, 0, 1024, stream);
  const bf_t* zrow = (const bf_t*)bsums;

  // ---- layer 0 input ----
  cvt_x<<<NN, 128, 0, stream>>>(x, Ab, flag);

  const int lda[4] = {512, 512, 1024, 1024};
  int aggBlocks = (NSEG + 3)/4;   // 4 waves per 256-block
  for (int l = 0; l < 4; ++l){
    int O = dou[l];
    if (DP[l] == 128)
      aggregate_wave<128><<<aggBlocks, 256, 0, stream>>>(Ab, lda[l], segoff, srcs, rcnt, zrow, Ab);
    else
      aggregate_wave<256><<<aggBlocks, 256, 0, stream>>>(Ab, lda[l], segoff, srcs, rcnt, zrow, Ab);

    hipMemsetAsync(sums, 0, 512*sizeof(float), stream);
    gemm_mfma2<256><<<dim3(196, 1), 1024, 0, stream>>>(Ab, lda[l], 4*DP[l], wt + wtoff[l], bfp[l],
                                                       C, Op[l], O, sums);

    bn_finalize<<<1, 256, 0, stream>>>(sums, gf[l], bbf[l], scale, shift, O);

    int DPN = (l < 3) ? DP[l+1] : 256;
    int ldan = (l < 3) ? lda[l+1] : 1024;
    if (DPN == 128)
      bn_cvt<128><<<NN, 128, 0, stream>>>(C, Op[l], O, scale, shift, Ab, ldan);
    else
      bn_cvt<256><<<NN, 256, 0, stream>>>(C, Op[l], O, scale, shift, Ab, ldan);
  }

  hipMemsetAsync(pooled, 0, (size_t)GG*256*sizeof(float), stream);
  pool_kernel<<<dim3(GG, 8), 256, 0, stream>>>(Ab + 768, batch, pooled);
  final_kernel<<<GG, 128, 0, stream>>>(pooled, metaf, w1f, b1f, w2f, b2f_, d_out, flag);
}

// Round 14
// 842.177 us; speedup vs baseline: 1.0043x; 1.0043x over previous
//
#include <hip/hip_runtime.h>
#include <hip/hip_bf16.h>

#define NN 50000
#define EE 800000
#define GG 64
#define RR 3
#define METAD 38
#define NSEG (RR*NN)
#define EPSV 1e-5f

typedef __bf16 bf_t;
typedef __attribute__((ext_vector_type(8))) __bf16 bf16x8;
typedef __attribute__((ext_vector_type(4))) __bf16 bf16x4;
typedef __attribute__((ext_vector_type(2))) __bf16 bf16x2;
typedef __attribute__((ext_vector_type(4))) float f32x4;
typedef __attribute__((address_space(1))) void gas_t;
typedef __attribute__((address_space(3))) void las_t;

__device__ __forceinline__ float loadf(const void* p, size_t i, int flag){
  return flag ? ((const float*)p)[i] : (float)(((const bf_t*)p)[i]);
}

// ---------------- dtype detector: fp32 (1) vs bf16 (0) ----------------
__global__ __launch_bounds__(256) void detect_kernel(const void* __restrict__ xraw,
                                                     int* __restrict__ flag){
  __shared__ int found;
  if (threadIdx.x == 0) found = 0;
  __syncthreads();
  const unsigned short* u = (const unsigned short*)xraw;
  for (int i = threadIdx.x; i < 65536; i += 256){
    int e = (u[i] >> 7) & 0xFF;
    if (e >= 0xF0) found = 1;
  }
  __syncthreads();
  if (threadIdx.x == 0) *flag = found;
}

// ---------------- merged small-param convert ----------------
struct CvtJobs {
  const void* src[17];
  float* dst[17];
  int n[17];
};

__global__ __launch_bounds__(256) void cvt_many(CvtJobs j, const int* __restrict__ flag){
  int job = blockIdx.y;
  int i = blockIdx.x*256 + threadIdx.x;
  if (i < j.n[job]) j.dst[job][i] = loadf(j.src[job], i, *flag);
}

// ---------------- pack weights: WbT[o][r*DP+i] = W[r][i][o] (bf16, zero-padded) ----------------
__global__ __launch_bounds__(256) void pack_w(const void* __restrict__ W,
                                              const void* __restrict__ R,
                                              bf_t* __restrict__ out,
                                              int D, int O, int dplog,
                                              const int* __restrict__ flag){
  int id = blockIdx.x*256 + threadIdx.x;
  int DP4 = 1 << (dplog + 2);
  int o = id >> (dplog + 2);
  int k = id & (DP4 - 1);
  int r = k >> dplog;
  int i = k & ((1 << dplog) - 1);
  float v = 0.f;
  int fl = *flag;
  if (i < D && o < O){
    if (r < 3) v = loadf(W, ((size_t)r*D + i)*O + o, fl);
    else       v = loadf(R, (size_t)i*O + o, fl);
  }
  out[(size_t)o*DP4 + k] = (bf_t)v;
}

// ---------------- CSR build ----------------
__global__ __launch_bounds__(256) void counti_kernel(const int* __restrict__ ei,
                                                     const int* __restrict__ et,
                                                     int* __restrict__ cnt){
  int e = blockIdx.x*256 + threadIdx.x;
  if (e < EE) atomicAdd(&cnt[et[e]*NN + ei[EE + e]], 1);
}

__global__ __launch_bounds__(256) void rcnt_kernel(const int* __restrict__ cnt,
                                                   float* __restrict__ rcnt){
  int i = blockIdx.x*256 + threadIdx.x;
  if (i < NSEG) rcnt[i] = 1.0f / (float)max(cnt[i], 1);
}

__global__ __launch_bounds__(256) void scan1_kernel(const int* __restrict__ cnt,
                                                    int* __restrict__ segoff,
                                                    int* __restrict__ bsums){
  __shared__ int sh[256];
  int i = blockIdx.x*256 + threadIdx.x;
  int v = (i < NSEG) ? cnt[i] : 0;
  sh[threadIdx.x] = v;
  __syncthreads();
  for (int off = 1; off < 256; off <<= 1){
    int t = 0;
    if (threadIdx.x >= off) t = sh[threadIdx.x - off];
    __syncthreads();
    if (threadIdx.x >= off) sh[threadIdx.x] += t;
    __syncthreads();
  }
  if (i < NSEG) segoff[i] = sh[threadIdx.x] - v;
  if (threadIdx.x == 255) bsums[blockIdx.x] = sh[255];
}

__global__ __launch_bounds__(256) void scan2_kernel(int* __restrict__ bsums, int nb){
  __shared__ int sh[256];
  __shared__ int carry;
  if (threadIdx.x == 0) carry = 0;
  __syncthreads();
  for (int base = 0; base < nb; base += 256){
    int i = base + threadIdx.x;
    int v = (i < nb) ? bsums[i] : 0;
    sh[threadIdx.x] = v;
    __syncthreads();
    for (int off = 1; off < 256; off <<= 1){
      int t = 0;
      if (threadIdx.x >= off) t = sh[threadIdx.x - off];
      __syncthreads();
      if (threadIdx.x >= off) sh[threadIdx.x] += t;
      __syncthreads();
    }
    if (i < nb) bsums[i] = sh[threadIdx.x] - v + carry;
    __syncthreads();
    if (threadIdx.x == 0) carry += sh[255];
    __syncthreads();
  }
}

__global__ __launch_bounds__(256) void scan3_kernel(int* __restrict__ segoff,
                                                    const int* __restrict__ bsums){
  int i = blockIdx.x*256 + threadIdx.x;
  if (i < NSEG) segoff[i] += bsums[blockIdx.x];
  if (i == 0) segoff[NSEG] = EE;
}

__global__ __launch_bounds__(256) void curinit_kernel(const int* __restrict__ segoff,
                                                      int* __restrict__ cursor){
  int i = blockIdx.x*256 + threadIdx.x;
  if (i < NSEG) cursor[i] = segoff[i];
}

__global__ __launch_bounds__(256) void place_kernel(const int* __restrict__ ei,
                                                    const int* __restrict__ et,
                                                    int* __restrict__ cursor,
                                                    int* __restrict__ srcs){
  int e = blockIdx.x*256 + threadIdx.x;
  if (e < EE){
    int seg = et[e]*NN + ei[EE + e];
    int pos = atomicAdd(&cursor[seg], 1);
    srcs[pos] = ei[e];
  }
}

// ---------------- x -> Ab slice3 (layer0, D=DP=128, lda=512) ----------------
__global__ __launch_bounds__(128) void cvt_x(const void* __restrict__ x,
                                             bf_t* __restrict__ Ab,
                                             const int* __restrict__ flag){
  int d = blockIdx.x, t = threadIdx.x;
  Ab[(size_t)d*512 + 384 + t] = (bf_t)loadf(x, (size_t)d*128 + t, *flag);
}

// ------- wave-per-segment CSR gather mean: exact 4-wide + ONE predicated tail trip -------
// R19-verified.  At roofline: E*D*2 = 410MB mandatory gather + 25MB write in
// 64us = 6.8 TB/s logical delivery (== the measured ceiling).  FROZEN.
template<int DP>
__global__ __launch_bounds__(256) void aggregate_wave(const bf_t* __restrict__ Ab, int lda,
                                                      const int* __restrict__ segoff,
                                                      const int* __restrict__ srcs,
                                                      const float* __restrict__ rcnt,
                                                      const bf_t* __restrict__ zrow,
                                                      bf_t* __restrict__ out){
  int wid = (blockIdx.x*256 + threadIdx.x) >> 6;
  if (wid >= NSEG) return;
  wid = __builtin_amdgcn_readfirstlane(wid);   // wave-uniform -> SGPR chain
  int lane = threadIdx.x & 63;
  int r = wid / NN;
  int d = wid - r*NN;
  int s0 = segoff[wid], s1 = segoff[wid + 1];
  float rc = rcnt[wid];
  const bf_t* in = Ab + 3*DP;

  if (DP == 256){
    float a0=0.f, a1=0.f, a2=0.f, a3=0.f;
    const int off = lane*4;
    const bf_t* zp = zrow + off;
    int e = s0;
    for (; e + 4 <= s1; e += 4){
      int sA = srcs[e], sB = srcs[e+1], sC = srcs[e+2], sD = srcs[e+3];
      uint2 vA = *(const uint2*)(in + (size_t)sA*lda + off);
      uint2 vB = *(const uint2*)(in + (size_t)sB*lda + off);
      uint2 vC = *(const uint2*)(in + (size_t)sC*lda + off);
      uint2 vD = *(const uint2*)(in + (size_t)sD*lda + off);
      a0 += __uint_as_float(vA.x << 16); a1 += __uint_as_float(vA.x & 0xFFFF0000u);
      a2 += __uint_as_float(vA.y << 16); a3 += __uint_as_float(vA.y & 0xFFFF0000u);
      a0 += __uint_as_float(vB.x << 16); a1 += __uint_as_float(vB.x & 0xFFFF0000u);
      a2 += __uint_as_float(vB.y << 16); a3 += __uint_as_float(vB.y & 0xFFFF0000u);
      a0 += __uint_as_float(vC.x << 16); a1 += __uint_as_float(vC.x & 0xFFFF0000u);
      a2 += __uint_as_float(vC.y << 16); a3 += __uint_as_float(vC.y & 0xFFFF0000u);
      a0 += __uint_as_float(vD.x << 16); a1 += __uint_as_float(vD.x & 0xFFFF0000u);
      a2 += __uint_as_float(vD.y << 16); a3 += __uint_as_float(vD.y & 0xFFFF0000u);
    }
    if (e < s1){                        // single predicated trip, <=3 loads, all independent
      int sA = srcs[e];
      int sB = srcs[min(e+1, s1-1)];
      int sC = srcs[min(e+2, s1-1)];
      const uint2* pA = (const uint2*)(in + (size_t)sA*lda + off);
      const uint2* pB = (e+1 < s1) ? (const uint2*)(in + (size_t)sB*lda + off) : (const uint2*)zp;
      const uint2* pC = (e+2 < s1) ? (const uint2*)(in + (size_t)sC*lda + off) : (const uint2*)zp;
      uint2 vA = *pA, vB = *pB, vC = *pC;
      a0 += __uint_as_float(vA.x << 16); a1 += __uint_as_float(vA.x & 0xFFFF0000u);
      a2 += __uint_as_float(vA.y << 16); a3 += __uint_as_float(vA.y & 0xFFFF0000u);
      a0 += __uint_as_float(vB.x << 16); a1 += __uint_as_float(vB.x & 0xFFFF0000u);
      a2 += __uint_as_float(vB.y << 16); a3 += __uint_as_float(vB.y & 0xFFFF0000u);
      a0 += __uint_as_float(vC.x << 16); a1 += __uint_as_float(vC.x & 0xFFFF0000u);
      a2 += __uint_as_float(vC.y << 16); a3 += __uint_as_float(vC.y & 0xFFFF0000u);
    }
    bf16x4 o = {(bf_t)(a0*rc), (bf_t)(a1*rc), (bf_t)(a2*rc), (bf_t)(a3*rc)};
    *(bf16x4*)(out + (size_t)d*lda + r*DP + off) = o;
  } else {
    float a0=0.f, a1=0.f;
    const int off = lane*2;
    const bf_t* zp = zrow + off;
    int e = s0;
    for (; e + 4 <= s1; e += 4){
      int sA = srcs[e], sB = srcs[e+1], sC = srcs[e+2], sD = srcs[e+3];
      unsigned vA = *(const unsigned*)(in + (size_t)sA*lda + off);
      unsigned vB = *(const unsigned*)(in + (size_t)sB*lda + off);
      unsigned vC = *(const unsigned*)(in + (size_t)sC*lda + off);
      unsigned vD = *(const unsigned*)(in + (size_t)sD*lda + off);
      a0 += __uint_as_float(vA << 16); a1 += __uint_as_float(vA & 0xFFFF0000u);
      a0 += __uint_as_float(vB << 16); a1 += __uint_as_float(vB & 0xFFFF0000u);
      a0 += __uint_as_float(vC << 16); a1 += __uint_as_float(vC & 0xFFFF0000u);
      a0 += __uint_as_float(vD << 16); a1 += __uint_as_float(vD & 0xFFFF0000u);
    }
    if (e < s1){
      int sA = srcs[e];
      int sB = srcs[min(e+1, s1-1)];
      int sC = srcs[min(e+2, s1-1)];
      const unsigned* pA = (const unsigned*)(in + (size_t)sA*lda + off);
      const unsigned* pB = (e+1 < s1) ? (const unsigned*)(in + (size_t)sB*lda + off) : (const unsigned*)zp;
      const unsigned* pC = (e+2 < s1) ? (const unsigned*)(in + (size_t)sC*lda + off) : (const unsigned*)zp;
      unsigned vA = *pA, vB = *pB, vC = *pC;
      a0 += __uint_as_float(vA << 16); a1 += __uint_as_float(vA & 0xFFFF0000u);
      a0 += __uint_as_float(vB << 16); a1 += __uint_as_float(vB & 0xFFFF0000u);
      a0 += __uint_as_float(vC << 16); a1 += __uint_as_float(vC & 0xFFFF0000u);
    }
    bf16x2 o = {(bf_t)(a0*rc), (bf_t)(a1*rc)};
    *(bf16x2*)(out + (size_t)d*lda + r*DP + off) = o;
  }
}

// ---------------- MFMA GEMM A: 128x128 tile (R12-verified, best for short K) ----------------
// R28 hybrid: this kernel serves l0/l1 (K=512) where 782-block occupancy wins;
// the 256x256 kernel below serves l2/l3 (K=1024) where staging reuse wins
// (R13: left top-5, <63.8us) but its 196-block grid is too coarse for short K
// (R13 e2e regression isolated to the short layers).
#define ISSUE4(B_, KO_)                                                                             \
  { uint4* _b = &lds4[B_][0];                                                                       \
    __builtin_amdgcn_global_load_lds((gas_t*)(Ar0 + (KO_)), (las_t*)(_b + ca0*64), 16, 0, 0);       \
    __builtin_amdgcn_global_load_lds((gas_t*)(Ar1 + (KO_)), (las_t*)(_b + ca1*64), 16, 0, 0);       \
    __builtin_amdgcn_global_load_lds((gas_t*)(Br0 + (KO_)), (las_t*)(_b + 128*8 + ca0*64), 16, 0, 0); \
    __builtin_amdgcn_global_load_lds((gas_t*)(Br1 + (KO_)), (las_t*)(_b + 128*8 + ca1*64), 16, 0, 0); }

template<int NT>
__global__ __launch_bounds__(512) void gemm_mfma2(const bf_t* __restrict__ A, int lda, int K,
                                                  const bf_t* __restrict__ Bt,
                                                  const float* __restrict__ bias,
                                                  bf_t* __restrict__ C, int ldc, int O,
                                                  float* __restrict__ sums){
  constexpr int NI = NT/64;              // 2 (only <128> is instantiated)
  __shared__ uint4 lds4[2][(128 + NT)*8];  // 2 x 32768 B double buffer
  __shared__ float colsum[2*NT];
  float* stage = (float*)lds4;           // epilogue overlay

  int tid = threadIdx.x;
  int lane = tid & 63;
  int wave = tid >> 6;                   // 0..7
  int row0 = blockIdx.x*128;
  int col0 = blockIdx.y*NT;
  int mw = (wave & 1) << 6;
  int nw = (wave >> 1) * (NT/4);
  int l15 = lane & 15, quad = lane >> 4;
  f32x4 acc[4][NI] = {};

  int lrow = lane >> 3;                  // 0..7
  int lk8  = ((lane & 7) ^ lrow) * 8;    // swizzled bf16 k-offset within 64
  int ca0 = wave*2, ca1 = wave*2 + 1;
  int gra0 = row0 + ca0*8 + lrow; if (gra0 >= NN) gra0 = NN - 1;
  int gra1 = row0 + ca1*8 + lrow; if (gra1 >= NN) gra1 = NN - 1;
  const bf_t* Ar0 = A + (size_t)gra0*lda + lk8;
  const bf_t* Ar1 = A + (size_t)gra1*lda + lk8;
  const bf_t* Br0 = Bt + (size_t)(col0 + ca0*8 + lrow)*K + lk8;
  const bf_t* Br1 = Bt + (size_t)(col0 + ca1*8 + lrow)*K + lk8;

  int niter = K >> 6;
  ISSUE4(0, 0)
  if (niter > 1) ISSUE4(1, 64)

  for (int i = 0; i < niter; ++i){
    if (i + 1 < niter) asm volatile("s_waitcnt vmcnt(4)" ::: "memory");
    else               asm volatile("s_waitcnt vmcnt(0)" ::: "memory");
    __builtin_amdgcn_s_barrier();
    asm volatile("" ::: "memory");
    __builtin_amdgcn_sched_barrier(0);

    const uint4* As4 = &lds4[i & 1][0];
    const uint4* Bs4 = As4 + 128*8;
    #pragma unroll
    for (int kk = 0; kk < 2; ++kk){
      bf16x8 af[4], bfv[NI];
      int ku = kk*4 + quad;
      int kswz = ku ^ (l15 & 7);
      #pragma unroll
      for (int mi = 0; mi < 4; ++mi){
        int R = mw + mi*16 + l15;
        af[mi] = *(const bf16x8*)&As4[R*8 + kswz];
      }
      #pragma unroll
      for (int ni = 0; ni < NI; ++ni){
        int Rb = nw + ni*16 + l15;
        bfv[ni] = *(const bf16x8*)&Bs4[Rb*8 + kswz];
      }
      #pragma unroll
      for (int mi = 0; mi < 4; ++mi)
        #pragma unroll
        for (int ni = 0; ni < NI; ++ni)
          acc[mi][ni] = __builtin_amdgcn_mfma_f32_16x16x32_bf16(af[mi], bfv[ni], acc[mi][ni], 0, 0, 0);
    }
    asm volatile("s_waitcnt lgkmcnt(0)" ::: "memory");
    __builtin_amdgcn_s_barrier();
    if (i + 2 < niter) ISSUE4(i & 1, (i + 2) << 6)
  }

  // ---- epilogue: BN partials + staged coalesced bf16 C store ----
  __syncthreads();
  if (tid < 2*NT) colsum[tid] = 0.f;
  float bzv[NI];
  #pragma unroll
  for (int ni = 0; ni < NI; ++ni){
    int col = col0 + nw + ni*16 + l15;
    bzv[ni] = (col < O) ? bias[col] : 0.f;
  }
  __syncthreads();

  #pragma unroll
  for (int ni = 0; ni < NI; ++ni){
    int lcol = nw + ni*16 + l15;
    int col = col0 + lcol;
    if (col < O){
      float scol = 0.f, qcol = 0.f;
      #pragma unroll
      for (int mi = 0; mi < 4; ++mi){
        int rb = row0 + mw + mi*16 + quad*4;
        #pragma unroll
        for (int j = 0; j < 4; ++j){
          if (rb + j < NN){
            float v = acc[mi][ni][j] + bzv[ni];
            scol += v; qcol += v*v;
          }
        }
      }
      atomicAdd(&colsum[lcol], scol);
      atomicAdd(&colsum[NT + lcol], qcol);
    }
  }

  constexpr int STR = NT + 4;
  constexpr int TPR = NT/4;          // 32 threads per row in store
  constexpr int RPR = 512/TPR;       // 16 rows per store round
  int rl0 = tid / TPR;
  int colg = (tid % TPR)*4;
  #pragma unroll
  for (int c = 0; c < 4; ++c){
    __syncthreads();
    if ((wave & 1) == (c >> 1)){
      int base = (c & 1)*32;
      #pragma unroll
      for (int m2 = 0; m2 < 2; ++m2){
        int mi = (base >> 4) + m2;
        #pragma unroll
        for (int ni = 0; ni < NI; ++ni)
          #pragma unroll
          for (int j = 0; j < 4; ++j)
            stage[(mi*16 + quad*4 + j - base)*STR + nw + ni*16 + l15] = acc[mi][ni][j] + bzv[ni];
      }
    }
    __syncthreads();
    #pragma unroll
    for (int p = 0; p < 32/RPR; ++p){
      int rl = p*RPR + rl0;
      int gr = row0 + c*32 + rl;
      if (gr < NN){
        float4 v4 = *(const float4*)&stage[rl*STR + colg];
        bf16x4 o = {(bf_t)v4.x, (bf_t)v4.y, (bf_t)v4.z, (bf_t)v4.w};
        *(bf16x4*)&C[(size_t)gr*ldc + col0 + colg] = o;
      }
    }
  }

  __syncthreads();
  for (int c = tid; c < NT; c += 512){
    int col = col0 + c;
    if (col < O){
      unsafeAtomicAdd(&sums[col], colsum[c]);
      unsafeAtomicAdd(&sums[256 + col], colsum[NT + c]);
    }
  }
}

// ------- MFMA GEMM B: 256x256 tile (R13-verified, best for K=1024 reuse) -------
#define BISSUE2(B_, KO_)                                                                            \
  { uint4* _b = &lds4[B_][0];                                                                       \
    __builtin_amdgcn_global_load_lds((gas_t*)(ArG + (KO_)), (las_t*)(_b + wave*64), 16, 0, 0);      \
    __builtin_amdgcn_global_load_lds((gas_t*)(BrG + (KO_)), (las_t*)(_b + 1024 + wave*64), 16, 0, 0); }

template<int NT>
__global__ __launch_bounds__(1024, 4) void gemm_big(const bf_t* __restrict__ A, int lda, int K,
                                                    const bf_t* __restrict__ Bt,
                                                    const float* __restrict__ bias,
                                                    bf_t* __restrict__ C, int ldc, int O,
                                                    float* __restrict__ sums){
  __shared__ uint4 lds4[2][2048];        // per buf: A 16KB (0..1023) + B 16KB (1024..2047)
  __shared__ float colsum[2*NT];         // 512 floats
  float* stage = (float*)lds4;           // epilogue overlay: 32 rows x 260 floats

  int tid = threadIdx.x;
  int lane = tid & 63;
  int wave = tid >> 6;                   // 0..15
  int wr = wave & 3, wc = wave >> 2;     // 4x4 grid of 64x64 wave tiles
  int row0 = blockIdx.x*256;
  int col0 = 0;
  int l15 = lane & 15, quad = lane >> 4;
  f32x4 acc[4][4] = {};

  int skc8 = ((lane & 3) ^ ((lane >> 3) & 3)) * 8;
  int arow = row0 + wave*16 + (lane >> 2); if (arow >= NN) arow = NN - 1;
  const bf_t* ArG = A + (size_t)arow*lda + skc8;
  const bf_t* BrG = Bt + (size_t)(col0 + wave*16 + (lane >> 2))*K + skc8;

  int niter = K >> 5;
  BISSUE2(0, 0)
  BISSUE2(1, 32)

  int sx = (l15 >> 1) & 3;               // read-side of the involution
  for (int i = 0; i < niter; ++i){
    if (i + 1 < niter) asm volatile("s_waitcnt vmcnt(2)" ::: "memory");
    else               asm volatile("s_waitcnt vmcnt(0)" ::: "memory");
    __builtin_amdgcn_s_barrier();
    asm volatile("" ::: "memory");
    __builtin_amdgcn_sched_barrier(0);

    const uint4* As4 = &lds4[i & 1][0];
    const uint4* Bs4 = As4 + 1024;
    bf16x8 af[4], bfv[4];
    #pragma unroll
    for (int mi = 0; mi < 4; ++mi){
      int R = wr*64 + mi*16 + l15;
      af[mi] = *(const bf16x8*)&As4[R*4 + (quad ^ sx)];
    }
    #pragma unroll
    for (int ni = 0; ni < 4; ++ni){
      int Rb = wc*64 + ni*16 + l15;
      bfv[ni] = *(const bf16x8*)&Bs4[Rb*4 + (quad ^ sx)];
    }
    #pragma unroll
    for (int mi = 0; mi < 4; ++mi)
      #pragma unroll
      for (int ni = 0; ni < 4; ++ni)
        acc[mi][ni] = __builtin_amdgcn_mfma_f32_16x16x32_bf16(af[mi], bfv[ni], acc[mi][ni], 0, 0, 0);

    asm volatile("s_waitcnt lgkmcnt(0)" ::: "memory");
    __builtin_amdgcn_s_barrier();
    if (i + 2 < niter) BISSUE2(i & 1, (i + 2) << 5)
  }

  // ---- epilogue: BN partials + staged coalesced bf16 C store (16-wave 64x64 layout) ----
  __syncthreads();
  if (tid < 2*NT) colsum[tid] = 0.f;
  float bzv[4];
  #pragma unroll
  for (int ni = 0; ni < 4; ++ni){
    int col = col0 + wc*64 + ni*16 + l15;
    bzv[ni] = (col < O) ? bias[col] : 0.f;
  }
  __syncthreads();

  #pragma unroll
  for (int ni = 0; ni < 4; ++ni){
    int lcol = wc*64 + ni*16 + l15;
    int col = col0 + lcol;
    if (col < O){
      float scol = 0.f, qcol = 0.f;
      #pragma unroll
      for (int mi = 0; mi < 4; ++mi){
        int rbase = row0 + wr*64 + mi*16 + quad*4;
        #pragma unroll
        for (int j = 0; j < 4; ++j){
          if (rbase + j < NN){
            float v = acc[mi][ni][j] + bzv[ni];
            scol += v; qcol += v*v;
          }
        }
      }
      atomicAdd(&colsum[lcol], scol);
      atomicAdd(&colsum[NT + lcol], qcol);
    }
  }

  constexpr int STR = NT + 4;            // 260 floats
  int rl0 = tid >> 5;                    // 0..31 (32 threads per row)
  int cg = (tid & 31)*8;                 // 8 cols per thread
  #pragma unroll
  for (int c = 0; c < 8; ++c){           // row chunks of 32
    __syncthreads();
    if (wr == (c >> 1)){
      int base = (c & 1)*32;
      #pragma unroll
      for (int m2 = 0; m2 < 2; ++m2){
        int mi = (c & 1)*2 + m2;
        #pragma unroll
        for (int ni = 0; ni < 4; ++ni)
          #pragma unroll
          for (int j = 0; j < 4; ++j)
            stage[(mi*16 + quad*4 + j - base)*STR + wc*64 + ni*16 + l15] = acc[mi][ni][j] + bzv[ni];
      }
    }
    __syncthreads();
    int gr = row0 + c*32 + rl0;
    if (gr < NN && cg < ldc){
      const float* sp = &stage[rl0*STR + cg];
      bf16x8 o = {(bf_t)sp[0], (bf_t)sp[1], (bf_t)sp[2], (bf_t)sp[3],
                  (bf_t)sp[4], (bf_t)sp[5], (bf_t)sp[6], (bf_t)sp[7]};
      *(bf16x8*)&C[(size_t)gr*ldc + col0 + cg] = o;
    }
  }

  __syncthreads();
  for (int c = tid; c < NT; c += 1024){
    int col = col0 + c;
    if (col < O){
      unsafeAtomicAdd(&sums[col], colsum[c]);
      unsafeAtomicAdd(&sums[256 + col], colsum[NT + c]);
    }
  }
}

// ---------------- BN finalize ----------------
__global__ __launch_bounds__(256) void bn_finalize(const float* __restrict__ sums,
                                                   const float* __restrict__ g,
                                                   const float* __restrict__ bb,
                                                   float* __restrict__ scale,
                                                   float* __restrict__ shift, int dout){
  int c = threadIdx.x;
  if (c < dout){
    float mu = sums[c] * (1.0f/NN);
    float var = sums[256 + c] * (1.0f/NN) - mu*mu;
    float rstd = rsqrtf(fmaxf(var, 0.f) + EPSV);
    float s = rstd * g[c];
    scale[c] = s;
    shift[c] = bb[c] - mu*s;
  }
}

// BN apply fused with bf16 convert into Ab slice3 (bf16 C input)
template<int DPN>
__global__ __launch_bounds__(DPN) void bn_cvt(const bf_t* __restrict__ C, int ldc, int O,
                                              const float* __restrict__ scale,
                                              const float* __restrict__ shift,
                                              bf_t* __restrict__ Ab, int ldan){
  int d = blockIdx.x, t = threadIdx.x;
  float v = 0.f;
  if (t < O) v = (float)C[(size_t)d*ldc + t]*scale[t] + shift[t];
  Ab[(size_t)d*ldan + 3*DPN + t] = (bf_t)v;
}

// ---------------- global mean pool (batch sorted, bf16 input from Ab slice3) ----------------
__device__ __forceinline__ int lower_bound(const int* __restrict__ a, int v){
  int lo = 0, hi = NN;
  while (lo < hi){ int m = (lo+hi) >> 1; if (a[m] < v) lo = m+1; else hi = m; }
  return lo;
}

__global__ __launch_bounds__(256) void pool_kernel(const bf_t* __restrict__ H,
                                                   const int* __restrict__ batch,
                                                   float* __restrict__ pooled){
  int g = blockIdx.x, sl = blockIdx.y;
  int start = lower_bound(batch, g), end = lower_bound(batch, g+1);
  int len = end - start;
  float inv = 1.0f / (float)max(len, 1);
  int chunk = (len + 7) >> 3;
  int s0 = start + sl*chunk;
  int s1 = min(s0 + chunk, end);
  float s = 0.f;
  for (int n = s0; n < s1; ++n) s += (float)H[(size_t)n*1024 + threadIdx.x];
  if (s1 > s0) unsafeAtomicAdd(&pooled[g*256 + threadIdx.x], s * inv);
}

// ---------------- final MLP ----------------
__global__ __launch_bounds__(128) void final_kernel(const float* __restrict__ pooled,
                                                    const float* __restrict__ meta,
                                                    const float* __restrict__ w1,
                                                    const float* __restrict__ b1,
                                                    const float* __restrict__ w2,
                                                    const float* __restrict__ b2,
                                                    void* __restrict__ out,
                                                    const int* __restrict__ flag){
  int g = blockIdx.x;
  __shared__ float h1[100];
  __shared__ float red[128];
  int t = threadIdx.x;
  if (t < 100){
    float acc = b1[t];
    for (int k = 0; k < 256; ++k) acc += pooled[g*256 + k] * w1[k*100 + t];
    for (int k = 0; k < METAD; ++k) acc += meta[g*METAD + k] * w1[(256+k)*100 + t];
    h1[t] = acc;
  }
  __syncthreads();
  red[t] = (t < 100) ? h1[t] * w2[t] : 0.f;
  __syncthreads();
  for (int s = 64; s > 0; s >>= 1){
    if (t < s) red[t] += red[t + s];
    __syncthreads();
  }
  if (t == 0){
    float v = red[0] + b2[0];
    if (*flag) ((float*)out)[g] = v;
    else       ((__hip_bfloat16*)out)[g] = __float2bfloat16(v);
  }
}

// ---------------- launch ----------------
extern "C" void kernel_launch(void* const* d_in, const int* in_sizes, int n_in,
                              void* d_out, int out_size, void* d_ws, size_t ws_size,
                              hipStream_t stream){
  const void* x    = d_in[0];
  const int*  ei   = (const int*)d_in[2];
  const int*  et   = (const int*)d_in[3];
  const int*  batch= (const int*)d_in[5];

  // ---- workspace layout (float units) ----
  float* ws     = (float*)d_ws;
  int*   flag   = (int*)ws;                    // 16
  float* rcnt   = ws + 16;                     // 150000 -> 150016
  int*   cnt    = (int*)(ws + 150016);         // -> (pad 300032)
  int*   segoff = (int*)(ws + 300032);         // 150001 -> (pad 450048)
  int*   bsums  = (int*)(ws + 450048);         // 1024 -> 451072 (dead after scan3 -> zero row)
  int*   srcs   = (int*)(ws + 451072);         // 800000 -> 1251072
  float* sums   = ws + 1251072;                // 512 -> 1251584
  float* scale  = ws + 1251584;                // 256
  float* shift  = ws + 1251840;                // 256
  float* pooled = ws + 1252096;                // 16384 -> 1268480
  float* bc     = ws + 1268480;                // 868
  float* gc_    = ws + 1269348;                // 868
  float* bbc    = ws + 1270216;                // 868
  float* metaf  = ws + 1271084;                // 2432
  float* w1f    = ws + 1273516;                // 29400
  float* b1f    = ws + 1302916;                // 100
  float* w2f    = ws + 1303016;                // 100
  float* b2f_   = ws + 1303116;                // 1 (pad 1303168)
  bf_t*  wt     = (bf_t*)(ws + 1303168);       // 720896 bf16 -> 1663616
  int*   cursor = (int*)(ws + 1663616);        // 150000 -> (pad 1813632)
  bf_t*  C      = (bf_t*)(ws + 1813632);       // 12.8M bf16 (25.6MB)
  bf_t*  Ab     = (bf_t*)(ws + 14613632);      // 51200000 bf16 -> 40213632 (160.9 MB)

  const size_t wtoff[4] = {0, 65536, 196608, 458752};

  detect_kernel<<<1, 256, 0, stream>>>(x, flag);

  // ---- merged small-param convert (17 jobs, one launch) ----
  const int vsz[4]  = {100, 256, 256, 256};
  const int voff[4] = {0, 100, 356, 612};
  float *bfp[4], *gf[4], *bbf[4];
  CvtJobs J;
  int nj = 0;
  for (int l = 0; l < 4; ++l){
    bfp[l] = bc + voff[l]; gf[l] = gc_ + voff[l]; bbf[l] = bbc + voff[l];
    J.src[nj] = d_in[6 + l*5 + 2]; J.dst[nj] = bfp[l]; J.n[nj] = vsz[l]; nj++;
    J.src[nj] = d_in[6 + l*5 + 3]; J.dst[nj] = gf[l];  J.n[nj] = vsz[l]; nj++;
    J.src[nj] = d_in[6 + l*5 + 4]; J.dst[nj] = bbf[l]; J.n[nj] = vsz[l]; nj++;
  }
  J.src[nj] = d_in[4];  J.dst[nj] = metaf; J.n[nj] = GG*METAD; nj++;
  J.src[nj] = d_in[26]; J.dst[nj] = w1f;   J.n[nj] = 29400; nj++;
  J.src[nj] = d_in[27]; J.dst[nj] = b1f;   J.n[nj] = 100; nj++;
  J.src[nj] = d_in[28]; J.dst[nj] = w2f;   J.n[nj] = 100; nj++;
  J.src[nj] = d_in[29]; J.dst[nj] = b2f_;  J.n[nj] = 1; nj++;
  cvt_many<<<dim3(115, nj), 256, 0, stream>>>(J, flag);

  // ---- pack weights to bf16 [Op][4*DP] ----
  const int din[4] = {128, 100, 256, 256};
  const int dou[4] = {100, 256, 256, 256};
  const int DP[4]  = {128, 128, 256, 256};
  const int dplog[4] = {7, 7, 8, 8};
  const int Op[4]  = {128, 256, 256, 256};
  for (int l = 0; l < 4; ++l){
    int total = Op[l] << (dplog[l] + 2);
    pack_w<<<total/256, 256, 0, stream>>>(d_in[6 + l*5 + 0], d_in[6 + l*5 + 1],
                                          wt + wtoff[l], din[l], dou[l], dplog[l], flag);
  }

  // ---- CSR build ----
  hipMemsetAsync(cnt, 0, NSEG*sizeof(int), stream);
  counti_kernel<<<(EE+255)/256, 256, 0, stream>>>(ei, et, cnt);
  rcnt_kernel<<<(NSEG+255)/256, 256, 0, stream>>>(cnt, rcnt);
  int nb = (NSEG + 255)/256;
  scan1_kernel<<<nb, 256, 0, stream>>>(cnt, segoff, bsums);
  scan2_kernel<<<1, 256, 0, stream>>>(bsums, nb);
  scan3_kernel<<<nb, 256, 0, stream>>>(segoff, bsums);
  curinit_kernel<<<nb, 256, 0, stream>>>(segoff, cursor);
  place_kernel<<<(EE+255)/256, 256, 0, stream>>>(ei, et, cursor, srcs);
  // bsums is dead now -> becomes the 512B zero row for predicated gathers
  hipMemsetAsync(bsums, 0, 1024, stream);
  const bf_t* zrow = (const bf_t*)bsums;

  // ---- layer 0 input ----
  cvt_x<<<NN, 128, 0, stream>>>(x, Ab, flag);

  const int lda[4] = {512, 512, 1024, 1024};
  int aggBlocks = (NSEG + 3)/4;   // 4 waves per 256-block
  for (int l = 0; l < 4; ++l){
    int O = dou[l];
    if (DP[l] == 128)
      aggregate_wave<128><<<aggBlocks, 256, 0, stream>>>(Ab, lda[l], segoff, srcs, rcnt, zrow, Ab);
    else
      aggregate_wave<256><<<aggBlocks, 256, 0, stream>>>(Ab, lda[l], segoff, srcs, rcnt, zrow, Ab);

    hipMemsetAsync(sums, 0, 512*sizeof(float), stream);
    if (l < 2){
      dim3 g2(391, Op[l]/128);
      gemm_mfma2<128><<<g2, 512, 0, stream>>>(Ab, lda[l], 4*DP[l], wt + wtoff[l], bfp[l],
                                              C, Op[l], O, sums);
    } else {
      gemm_big<256><<<196, 1024, 0, stream>>>(Ab, lda[l], 4*DP[l], wt + wtoff[l], bfp[l],
                                              C, Op[l], O, sums);
    }

    bn_finalize<<<1, 256, 0, stream>>>(sums, gf[l], bbf[l], scale, shift, O);

    int DPN = (l < 3) ? DP[l+1] : 256;
    int ldan = (l < 3) ? lda[l+1] : 1024;
    if (DPN == 128)
      bn_cvt<128><<<NN, 128, 0, stream>>>(C, Op[l], O, scale, shift, Ab, ldan);
    else
      bn_cvt<256><<<NN, 256, 0, stream>>>(C, Op[l], O, scale, shift, Ab, ldan);
  }

  hipMemsetAsync(pooled, 0, (size_t)GG*256*sizeof(float), stream);
  pool_kernel<<<dim3(GG, 8), 256, 0, stream>>>(Ab + 768, batch, pooled);
  final_kernel<<<GG, 128, 0, stream>>>(pooled, metaf, w1f, b1f, w2f, b2f_, d_out, flag);
}

// Round 15
// 825.409 us; speedup vs baseline: 1.0247x; 1.0203x over previous
//
#include <hip/hip_runtime.h>
#include <hip/hip_bf16.h>

#define NN 50000
#define EE 800000
#define GG 64
#define RR 3
#define METAD 38
#define NSEG (RR*NN)
#define EPSV 1e-5f

typedef __bf16 bf_t;
typedef __attribute__((ext_vector_type(8))) __bf16 bf16x8;
typedef __attribute__((ext_vector_type(4))) __bf16 bf16x4;
typedef __attribute__((ext_vector_type(2))) __bf16 bf16x2;
typedef __attribute__((ext_vector_type(4))) float f32x4;
typedef __attribute__((address_space(1))) void gas_t;
typedef __attribute__((address_space(3))) void las_t;

__device__ __forceinline__ float loadf(const void* p, size_t i, int flag){
  return flag ? ((const float*)p)[i] : (float)(((const bf_t*)p)[i]);
}

// ---------------- dtype detector: fp32 (1) vs bf16 (0) ----------------
__global__ __launch_bounds__(256) void detect_kernel(const void* __restrict__ xraw,
                                                     int* __restrict__ flag){
  __shared__ int found;
  if (threadIdx.x == 0) found = 0;
  __syncthreads();
  const unsigned short* u = (const unsigned short*)xraw;
  for (int i = threadIdx.x; i < 65536; i += 256){
    int e = (u[i] >> 7) & 0xFF;
    if (e >= 0xF0) found = 1;
  }
  __syncthreads();
  if (threadIdx.x == 0) *flag = found;
}

// ---------------- merged small-param convert ----------------
struct CvtJobs {
  const void* src[17];
  float* dst[17];
  int n[17];
};

__global__ __launch_bounds__(256) void cvt_many(CvtJobs j, const int* __restrict__ flag){
  int job = blockIdx.y;
  int i = blockIdx.x*256 + threadIdx.x;
  if (i < j.n[job]) j.dst[job][i] = loadf(j.src[job], i, *flag);
}

// ---------------- pack weights: WbT[o][r*DP+i] = W[r][i][o] (bf16, zero-padded) ----------------
__global__ __launch_bounds__(256) void pack_w(const void* __restrict__ W,
                                              const void* __restrict__ R,
                                              bf_t* __restrict__ out,
                                              int D, int O, int dplog,
                                              const int* __restrict__ flag){
  int id = blockIdx.x*256 + threadIdx.x;
  int DP4 = 1 << (dplog + 2);
  int o = id >> (dplog + 2);
  int k = id & (DP4 - 1);
  int r = k >> dplog;
  int i = k & ((1 << dplog) - 1);
  float v = 0.f;
  int fl = *flag;
  if (i < D && o < O){
    if (r < 3) v = loadf(W, ((size_t)r*D + i)*O + o, fl);
    else       v = loadf(R, (size_t)i*O + o, fl);
  }
  out[(size_t)o*DP4 + k] = (bf_t)v;
}

// ---------------- CSR build ----------------
__global__ __launch_bounds__(256) void counti_kernel(const int* __restrict__ ei,
                                                     const int* __restrict__ et,
                                                     int* __restrict__ cnt){
  int e = blockIdx.x*256 + threadIdx.x;
  if (e < EE) atomicAdd(&cnt[et[e]*NN + ei[EE + e]], 1);
}

__global__ __launch_bounds__(256) void rcnt_kernel(const int* __restrict__ cnt,
                                                   float* __restrict__ rcnt){
  int i = blockIdx.x*256 + threadIdx.x;
  if (i < NSEG) rcnt[i] = 1.0f / (float)max(cnt[i], 1);
}

__global__ __launch_bounds__(256) void scan1_kernel(const int* __restrict__ cnt,
                                                    int* __restrict__ segoff,
                                                    int* __restrict__ bsums){
  __shared__ int sh[256];
  int i = blockIdx.x*256 + threadIdx.x;
  int v = (i < NSEG) ? cnt[i] : 0;
  sh[threadIdx.x] = v;
  __syncthreads();
  for (int off = 1; off < 256; off <<= 1){
    int t = 0;
    if (threadIdx.x >= off) t = sh[threadIdx.x - off];
    __syncthreads();
    if (threadIdx.x >= off) sh[threadIdx.x] += t;
    __syncthreads();
  }
  if (i < NSEG) segoff[i] = sh[threadIdx.x] - v;
  if (threadIdx.x == 255) bsums[blockIdx.x] = sh[255];
}

__global__ __launch_bounds__(256) void scan2_kernel(int* __restrict__ bsums, int nb){
  __shared__ int sh[256];
  __shared__ int carry;
  if (threadIdx.x == 0) carry = 0;
  __syncthreads();
  for (int base = 0; base < nb; base += 256){
    int i = base + threadIdx.x;
    int v = (i < nb) ? bsums[i] : 0;
    sh[threadIdx.x] = v;
    __syncthreads();
    for (int off = 1; off < 256; off <<= 1){
      int t = 0;
      if (threadIdx.x >= off) t = sh[threadIdx.x - off];
      __syncthreads();
      if (threadIdx.x >= off) sh[threadIdx.x] += t;
      __syncthreads();
    }
    if (i < nb) bsums[i] = sh[threadIdx.x] - v + carry;
    __syncthreads();
    if (threadIdx.x == 0) carry += sh[255];
    __syncthreads();
  }
}

__global__ __launch_bounds__(256) void scan3_kernel(int* __restrict__ segoff,
                                                    const int* __restrict__ bsums){
  int i = blockIdx.x*256 + threadIdx.x;
  if (i < NSEG) segoff[i] += bsums[blockIdx.x];
  if (i == 0) segoff[NSEG] = EE;
}

__global__ __launch_bounds__(256) void curinit_kernel(const int* __restrict__ segoff,
                                                      int* __restrict__ cursor){
  int i = blockIdx.x*256 + threadIdx.x;
  if (i < NSEG) cursor[i] = segoff[i];
}

__global__ __launch_bounds__(256) void place_kernel(const int* __restrict__ ei,
                                                    const int* __restrict__ et,
                                                    int* __restrict__ cursor,
                                                    int* __restrict__ srcs){
  int e = blockIdx.x*256 + threadIdx.x;
  if (e < EE){
    int seg = et[e]*NN + ei[EE + e];
    int pos = atomicAdd(&cursor[seg], 1);
    srcs[pos] = ei[e];
  }
}

// ---------------- x -> Ab slice3 (layer0, D=DP=128, lda=512) ----------------
__global__ __launch_bounds__(128) void cvt_x(const void* __restrict__ x,
                                             bf_t* __restrict__ Ab,
                                             const int* __restrict__ flag){
  int d = blockIdx.x, t = threadIdx.x;
  Ab[(size_t)d*512 + 384 + t] = (bf_t)loadf(x, (size_t)d*128 + t, *flag);
}

// ------- wave-per-segment CSR gather mean: exact 4-wide + ONE predicated tail trip -------
// R19-verified.  At roofline: E*D*2 = 410MB mandatory gather + 25MB write in
// 64us = 6.8 TB/s logical delivery (== the measured ceiling).  FROZEN.
template<int DP>
__global__ __launch_bounds__(256) void aggregate_wave(const bf_t* __restrict__ Ab, int lda,
                                                      const int* __restrict__ segoff,
                                                      const int* __restrict__ srcs,
                                                      const float* __restrict__ rcnt,
                                                      const bf_t* __restrict__ zrow,
                                                      bf_t* __restrict__ out){
  int wid = (blockIdx.x*256 + threadIdx.x) >> 6;
  if (wid >= NSEG) return;
  wid = __builtin_amdgcn_readfirstlane(wid);   // wave-uniform -> SGPR chain
  int lane = threadIdx.x & 63;
  int r = wid / NN;
  int d = wid - r*NN;
  int s0 = segoff[wid], s1 = segoff[wid + 1];
  float rc = rcnt[wid];
  const bf_t* in = Ab + 3*DP;

  if (DP == 256){
    float a0=0.f, a1=0.f, a2=0.f, a3=0.f;
    const int off = lane*4;
    const bf_t* zp = zrow + off;
    int e = s0;
    for (; e + 4 <= s1; e += 4){
      int sA = srcs[e], sB = srcs[e+1], sC = srcs[e+2], sD = srcs[e+3];
      uint2 vA = *(const uint2*)(in + (size_t)sA*lda + off);
      uint2 vB = *(const uint2*)(in + (size_t)sB*lda + off);
      uint2 vC = *(const uint2*)(in + (size_t)sC*lda + off);
      uint2 vD = *(const uint2*)(in + (size_t)sD*lda + off);
      a0 += __uint_as_float(vA.x << 16); a1 += __uint_as_float(vA.x & 0xFFFF0000u);
      a2 += __uint_as_float(vA.y << 16); a3 += __uint_as_float(vA.y & 0xFFFF0000u);
      a0 += __uint_as_float(vB.x << 16); a1 += __uint_as_float(vB.x & 0xFFFF0000u);
      a2 += __uint_as_float(vB.y << 16); a3 += __uint_as_float(vB.y & 0xFFFF0000u);
      a0 += __uint_as_float(vC.x << 16); a1 += __uint_as_float(vC.x & 0xFFFF0000u);
      a2 += __uint_as_float(vC.y << 16); a3 += __uint_as_float(vC.y & 0xFFFF0000u);
      a0 += __uint_as_float(vD.x << 16); a1 += __uint_as_float(vD.x & 0xFFFF0000u);
      a2 += __uint_as_float(vD.y << 16); a3 += __uint_as_float(vD.y & 0xFFFF0000u);
    }
    if (e < s1){                        // single predicated trip, <=3 loads, all independent
      int sA = srcs[e];
      int sB = srcs[min(e+1, s1-1)];
      int sC = srcs[min(e+2, s1-1)];
      const uint2* pA = (const uint2*)(in + (size_t)sA*lda + off);
      const uint2* pB = (e+1 < s1) ? (const uint2*)(in + (size_t)sB*lda + off) : (const uint2*)zp;
      const uint2* pC = (e+2 < s1) ? (const uint2*)(in + (size_t)sC*lda + off) : (const uint2*)zp;
      uint2 vA = *pA, vB = *pB, vC = *pC;
      a0 += __uint_as_float(vA.x << 16); a1 += __uint_as_float(vA.x & 0xFFFF0000u);
      a2 += __uint_as_float(vA.y << 16); a3 += __uint_as_float(vA.y & 0xFFFF0000u);
      a0 += __uint_as_float(vB.x << 16); a1 += __uint_as_float(vB.x & 0xFFFF0000u);
      a2 += __uint_as_float(vB.y << 16); a3 += __uint_as_float(vB.y & 0xFFFF0000u);
      a0 += __uint_as_float(vC.x << 16); a1 += __uint_as_float(vC.x & 0xFFFF0000u);
      a2 += __uint_as_float(vC.y << 16); a3 += __uint_as_float(vC.y & 0xFFFF0000u);
    }
    bf16x4 o = {(bf_t)(a0*rc), (bf_t)(a1*rc), (bf_t)(a2*rc), (bf_t)(a3*rc)};
    *(bf16x4*)(out + (size_t)d*lda + r*DP + off) = o;
  } else {
    float a0=0.f, a1=0.f;
    const int off = lane*2;
    const bf_t* zp = zrow + off;
    int e = s0;
    for (; e + 4 <= s1; e += 4){
      int sA = srcs[e], sB = srcs[e+1], sC = srcs[e+2], sD = srcs[e+3];
      unsigned vA = *(const unsigned*)(in + (size_t)sA*lda + off);
      unsigned vB = *(const unsigned*)(in + (size_t)sB*lda + off);
      unsigned vC = *(const unsigned*)(in + (size_t)sC*lda + off);
      unsigned vD = *(const unsigned*)(in + (size_t)sD*lda + off);
      a0 += __uint_as_float(vA << 16); a1 += __uint_as_float(vA & 0xFFFF0000u);
      a0 += __uint_as_float(vB << 16); a1 += __uint_as_float(vB & 0xFFFF0000u);
      a0 += __uint_as_float(vC << 16); a1 += __uint_as_float(vC & 0xFFFF0000u);
      a0 += __uint_as_float(vD << 16); a1 += __uint_as_float(vD & 0xFFFF0000u);
    }
    if (e < s1){
      int sA = srcs[e];
      int sB = srcs[min(e+1, s1-1)];
      int sC = srcs[min(e+2, s1-1)];
      const unsigned* pA = (const unsigned*)(in + (size_t)sA*lda + off);
      const unsigned* pB = (e+1 < s1) ? (const unsigned*)(in + (size_t)sB*lda + off) : (const unsigned*)zp;
      const unsigned* pC = (e+2 < s1) ? (const unsigned*)(in + (size_t)sC*lda + off) : (const unsigned*)zp;
      unsigned vA = *pA, vB = *pB, vC = *pC;
      a0 += __uint_as_float(vA << 16); a1 += __uint_as_float(vA & 0xFFFF0000u);
      a0 += __uint_as_float(vB << 16); a1 += __uint_as_float(vB & 0xFFFF0000u);
      a0 += __uint_as_float(vC << 16); a1 += __uint_as_float(vC & 0xFFFF0000u);
    }
    bf16x2 o = {(bf_t)(a0*rc), (bf_t)(a1*rc)};
    *(bf16x2*)(out + (size_t)d*lda + r*DP + off) = o;
  }
}

// ---------------- MFMA GEMM: R12 config (best measured e2e 829.6us) ----------------
// R29 = exact revert to the R12 kernel.  Evidence: R12 (all-128x128, bf16-C)
// = 829.6us e2e; R13 (all-256x256) = 845.8; R14 (hybrid) = 842.2.  The 256x256
// tile's per-dispatch gain (~2us) is outweighed by its 196-block grid (0.77
// blocks/CU, ~23% of CUs idle + serialized tail) -> tile-reuse is net-null for
// this problem (R13's pre-committed asymmetric read fired).  Both phases are
// now at measured limits: aggregate at the 6.8 TB/s logical-byte roofline,
// GEMM pinned 63-72us across seven structural variants with traffic already
// minimized (bf16 C).  BK=64, 8 waves, 2x32KB dbuf, vmcnt(4) counted, XOR
// kslot swizzle (conflicts==0 HW-verified).
#define ISSUE4(B_, KO_)                                                                             \
  { uint4* _b = &lds4[B_][0];                                                                       \
    __builtin_amdgcn_global_load_lds((gas_t*)(Ar0 + (KO_)), (las_t*)(_b + ca0*64), 16, 0, 0);       \
    __builtin_amdgcn_global_load_lds((gas_t*)(Ar1 + (KO_)), (las_t*)(_b + ca1*64), 16, 0, 0);       \
    __builtin_amdgcn_global_load_lds((gas_t*)(Br0 + (KO_)), (las_t*)(_b + 128*8 + ca0*64), 16, 0, 0); \
    __builtin_amdgcn_global_load_lds((gas_t*)(Br1 + (KO_)), (las_t*)(_b + 128*8 + ca1*64), 16, 0, 0); }

template<int NT>
__global__ __launch_bounds__(512) void gemm_mfma2(const bf_t* __restrict__ A, int lda, int K,
                                                  const bf_t* __restrict__ Bt,
                                                  const float* __restrict__ bias,
                                                  bf_t* __restrict__ C, int ldc, int O,
                                                  float* __restrict__ sums){
  constexpr int NI = NT/64;              // 2 (only <128> is instantiated)
  __shared__ uint4 lds4[2][(128 + NT)*8];  // 2 x 32768 B double buffer
  __shared__ float colsum[2*NT];
  float* stage = (float*)lds4;           // epilogue overlay

  int tid = threadIdx.x;
  int lane = tid & 63;
  int wave = tid >> 6;                   // 0..7
  int row0 = blockIdx.x*128;
  int col0 = blockIdx.y*NT;
  int mw = (wave & 1) << 6;
  int nw = (wave >> 1) * (NT/4);
  int l15 = lane & 15, quad = lane >> 4;
  f32x4 acc[4][NI] = {};

  int lrow = lane >> 3;                  // 0..7
  int lk8  = ((lane & 7) ^ lrow) * 8;    // swizzled bf16 k-offset within 64
  int ca0 = wave*2, ca1 = wave*2 + 1;
  int gra0 = row0 + ca0*8 + lrow; if (gra0 >= NN) gra0 = NN - 1;
  int gra1 = row0 + ca1*8 + lrow; if (gra1 >= NN) gra1 = NN - 1;
  const bf_t* Ar0 = A + (size_t)gra0*lda + lk8;
  const bf_t* Ar1 = A + (size_t)gra1*lda + lk8;
  const bf_t* Br0 = Bt + (size_t)(col0 + ca0*8 + lrow)*K + lk8;
  const bf_t* Br1 = Bt + (size_t)(col0 + ca1*8 + lrow)*K + lk8;

  int niter = K >> 6;
  ISSUE4(0, 0)
  if (niter > 1) ISSUE4(1, 64)

  for (int i = 0; i < niter; ++i){
    if (i + 1 < niter) asm volatile("s_waitcnt vmcnt(4)" ::: "memory");
    else               asm volatile("s_waitcnt vmcnt(0)" ::: "memory");
    __builtin_amdgcn_s_barrier();
    asm volatile("" ::: "memory");
    __builtin_amdgcn_sched_barrier(0);

    const uint4* As4 = &lds4[i & 1][0];
    const uint4* Bs4 = As4 + 128*8;
    #pragma unroll
    for (int kk = 0; kk < 2; ++kk){
      bf16x8 af[4], bfv[NI];
      int ku = kk*4 + quad;
      int kswz = ku ^ (l15 & 7);
      #pragma unroll
      for (int mi = 0; mi < 4; ++mi){
        int R = mw + mi*16 + l15;
        af[mi] = *(const bf16x8*)&As4[R*8 + kswz];
      }
      #pragma unroll
      for (int ni = 0; ni < NI; ++ni){
        int Rb = nw + ni*16 + l15;
        bfv[ni] = *(const bf16x8*)&Bs4[Rb*8 + kswz];
      }
      #pragma unroll
      for (int mi = 0; mi < 4; ++mi)
        #pragma unroll
        for (int ni = 0; ni < NI; ++ni)
          acc[mi][ni] = __builtin_amdgcn_mfma_f32_16x16x32_bf16(af[mi], bfv[ni], acc[mi][ni], 0, 0, 0);
    }
    asm volatile("s_waitcnt lgkmcnt(0)" ::: "memory");
    __builtin_amdgcn_s_barrier();
    if (i + 2 < niter) ISSUE4(i & 1, (i + 2) << 6)
  }

  // ---- epilogue: BN partials + staged coalesced bf16 C store ----
  __syncthreads();
  if (tid < 2*NT) colsum[tid] = 0.f;
  float bzv[NI];
  #pragma unroll
  for (int ni = 0; ni < NI; ++ni){
    int col = col0 + nw + ni*16 + l15;
    bzv[ni] = (col < O) ? bias[col] : 0.f;
  }
  __syncthreads();

  #pragma unroll
  for (int ni = 0; ni < NI; ++ni){
    int lcol = nw + ni*16 + l15;
    int col = col0 + lcol;
    if (col < O){
      float scol = 0.f, qcol = 0.f;
      #pragma unroll
      for (int mi = 0; mi < 4; ++mi){
        int rb = row0 + mw + mi*16 + quad*4;
        #pragma unroll
        for (int j = 0; j < 4; ++j){
          if (rb + j < NN){
            float v = acc[mi][ni][j] + bzv[ni];
            scol += v; qcol += v*v;
          }
        }
      }
      atomicAdd(&colsum[lcol], scol);
      atomicAdd(&colsum[NT + lcol], qcol);
    }
  }

  constexpr int STR = NT + 4;
  constexpr int TPR = NT/4;          // 32 threads per row in store
  constexpr int RPR = 512/TPR;       // 16 rows per store round
  int rl0 = tid / TPR;
  int colg = (tid % TPR)*4;
  #pragma unroll
  for (int c = 0; c < 4; ++c){
    __syncthreads();
    if ((wave & 1) == (c >> 1)){
      int base = (c & 1)*32;
      #pragma unroll
      for (int m2 = 0; m2 < 2; ++m2){
        int mi = (base >> 4) + m2;
        #pragma unroll
        for (int ni = 0; ni < NI; ++ni)
          #pragma unroll
          for (int j = 0; j < 4; ++j)
            stage[(mi*16 + quad*4 + j - base)*STR + nw + ni*16 + l15] = acc[mi][ni][j] + bzv[ni];
      }
    }
    __syncthreads();
    #pragma unroll
    for (int p = 0; p < 32/RPR; ++p){
      int rl = p*RPR + rl0;
      int gr = row0 + c*32 + rl;
      if (gr < NN){
        float4 v4 = *(const float4*)&stage[rl*STR + colg];
        bf16x4 o = {(bf_t)v4.x, (bf_t)v4.y, (bf_t)v4.z, (bf_t)v4.w};
        *(bf16x4*)&C[(size_t)gr*ldc + col0 + colg] = o;
      }
    }
  }

  __syncthreads();
  for (int c = tid; c < NT; c += 512){
    int col = col0 + c;
    if (col < O){
      unsafeAtomicAdd(&sums[col], colsum[c]);
      unsafeAtomicAdd(&sums[256 + col], colsum[NT + c]);
    }
  }
}

// ---------------- BN finalize ----------------
__global__ __launch_bounds__(256) void bn_finalize(const float* __restrict__ sums,
                                                   const float* __restrict__ g,
                                                   const float* __restrict__ bb,
                                                   float* __restrict__ scale,
                                                   float* __restrict__ shift, int dout){
  int c = threadIdx.x;
  if (c < dout){
    float mu = sums[c] * (1.0f/NN);
    float var = sums[256 + c] * (1.0f/NN) - mu*mu;
    float rstd = rsqrtf(fmaxf(var, 0.f) + EPSV);
    float s = rstd * g[c];
    scale[c] = s;
    shift[c] = bb[c] - mu*s;
  }
}

// BN apply fused with bf16 convert into Ab slice3 (bf16 C input)
template<int DPN>
__global__ __launch_bounds__(DPN) void bn_cvt(const bf_t* __restrict__ C, int ldc, int O,
                                              const float* __restrict__ scale,
                                              const float* __restrict__ shift,
                                              bf_t* __restrict__ Ab, int ldan){
  int d = blockIdx.x, t = threadIdx.x;
  float v = 0.f;
  if (t < O) v = (float)C[(size_t)d*ldc + t]*scale[t] + shift[t];
  Ab[(size_t)d*ldan + 3*DPN + t] = (bf_t)v;
}

// ---------------- global mean pool (batch sorted, bf16 input from Ab slice3) ----------------
__device__ __forceinline__ int lower_bound(const int* __restrict__ a, int v){
  int lo = 0, hi = NN;
  while (lo < hi){ int m = (lo+hi) >> 1; if (a[m] < v) lo = m+1; else hi = m; }
  return lo;
}

__global__ __launch_bounds__(256) void pool_kernel(const bf_t* __restrict__ H,
                                                   const int* __restrict__ batch,
                                                   float* __restrict__ pooled){
  int g = blockIdx.x, sl = blockIdx.y;
  int start = lower_bound(batch, g), end = lower_bound(batch, g+1);
  int len = end - start;
  float inv = 1.0f / (float)max(len, 1);
  int chunk = (len + 7) >> 3;
  int s0 = start + sl*chunk;
  int s1 = min(s0 + chunk, end);
  float s = 0.f;
  for (int n = s0; n < s1; ++n) s += (float)H[(size_t)n*1024 + threadIdx.x];
  if (s1 > s0) unsafeAtomicAdd(&pooled[g*256 + threadIdx.x], s * inv);
}

// ---------------- final MLP ----------------
__global__ __launch_bounds__(128) void final_kernel(const float* __restrict__ pooled,
                                                    const float* __restrict__ meta,
                                                    const float* __restrict__ w1,
                                                    const float* __restrict__ b1,
                                                    const float* __restrict__ w2,
                                                    const float* __restrict__ b2,
                                                    void* __restrict__ out,
                                                    const int* __restrict__ flag){
  int g = blockIdx.x;
  __shared__ float h1[100];
  __shared__ float red[128];
  int t = threadIdx.x;
  if (t < 100){
    float acc = b1[t];
    for (int k = 0; k < 256; ++k) acc += pooled[g*256 + k] * w1[k*100 + t];
    for (int k = 0; k < METAD; ++k) acc += meta[g*METAD + k] * w1[(256+k)*100 + t];
    h1[t] = acc;
  }
  __syncthreads();
  red[t] = (t < 100) ? h1[t] * w2[t] : 0.f;
  __syncthreads();
  for (int s = 64; s > 0; s >>= 1){
    if (t < s) red[t] += red[t + s];
    __syncthreads();
  }
  if (t == 0){
    float v = red[0] + b2[0];
    if (*flag) ((float*)out)[g] = v;
    else       ((__hip_bfloat16*)out)[g] = __float2bfloat16(v);
  }
}

// ---------------- launch ----------------
extern "C" void kernel_launch(void* const* d_in, const int* in_sizes, int n_in,
                              void* d_out, int out_size, void* d_ws, size_t ws_size,
                              hipStream_t stream){
  const void* x    = d_in[0];
  const int*  ei   = (const int*)d_in[2];
  const int*  et   = (const int*)d_in[3];
  const int*  batch= (const int*)d_in[5];

  // ---- workspace layout (float units) ----
  float* ws     = (float*)d_ws;
  int*   flag   = (int*)ws;                    // 16
  float* rcnt   = ws + 16;                     // 150000 -> 150016
  int*   cnt    = (int*)(ws + 150016);         // -> (pad 300032)
  int*   segoff = (int*)(ws + 300032);         // 150001 -> (pad 450048)
  int*   bsums  = (int*)(ws + 450048);         // 1024 -> 451072 (dead after scan3 -> zero row)
  int*   srcs   = (int*)(ws + 451072);         // 800000 -> 1251072
  float* sums   = ws + 1251072;                // 512 -> 1251584
  float* scale  = ws + 1251584;                // 256
  float* shift  = ws + 1251840;                // 256
  float* pooled = ws + 1252096;                // 16384 -> 1268480
  float* bc     = ws + 1268480;                // 868
  float* gc_    = ws + 1269348;                // 868
  float* bbc    = ws + 1270216;                // 868
  float* metaf  = ws + 1271084;                // 2432
  float* w1f    = ws + 1273516;                // 29400
  float* b1f    = ws + 1302916;                // 100
  float* w2f    = ws + 1303016;                // 100
  float* b2f_   = ws + 1303116;                // 1 (pad 1303168)
  bf_t*  wt     = (bf_t*)(ws + 1303168);       // 720896 bf16 -> 1663616
  int*   cursor = (int*)(ws + 1663616);        // 150000 -> (pad 1813632)
  bf_t*  C      = (bf_t*)(ws + 1813632);       // 12.8M bf16 (25.6MB)
  bf_t*  Ab     = (bf_t*)(ws + 14613632);      // 51200000 bf16 -> 40213632 (160.9 MB)

  const size_t wtoff[4] = {0, 65536, 196608, 458752};

  detect_kernel<<<1, 256, 0, stream>>>(x, flag);

  // ---- merged small-param convert (17 jobs, one launch) ----
  const int vsz[4]  = {100, 256, 256, 256};
  const int voff[4] = {0, 100, 356, 612};
  float *bfp[4], *gf[4], *bbf[4];
  CvtJobs J;
  int nj = 0;
  for (int l = 0; l < 4; ++l){
    bfp[l] = bc + voff[l]; gf[l] = gc_ + voff[l]; bbf[l] = bbc + voff[l];
    J.src[nj] = d_in[6 + l*5 + 2]; J.dst[nj] = bfp[l]; J.n[nj] = vsz[l]; nj++;
    J.src[nj] = d_in[6 + l*5 + 3]; J.dst[nj] = gf[l];  J.n[nj] = vsz[l]; nj++;
    J.src[nj] = d_in[6 + l*5 + 4]; J.dst[nj] = bbf[l]; J.n[nj] = vsz[l]; nj++;
  }
  J.src[nj] = d_in[4];  J.dst[nj] = metaf; J.n[nj] = GG*METAD; nj++;
  J.src[nj] = d_in[26]; J.dst[nj] = w1f;   J.n[nj] = 29400; nj++;
  J.src[nj] = d_in[27]; J.dst[nj] = b1f;   J.n[nj] = 100; nj++;
  J.src[nj] = d_in[28]; J.dst[nj] = w2f;   J.n[nj] = 100; nj++;
  J.src[nj] = d_in[29]; J.dst[nj] = b2f_;  J.n[nj] = 1; nj++;
  cvt_many<<<dim3(115, nj), 256, 0, stream>>>(J, flag);

  // ---- pack weights to bf16 [Op][4*DP] ----
  const int din[4] = {128, 100, 256, 256};
  const int dou[4] = {100, 256, 256, 256};
  const int DP[4]  = {128, 128, 256, 256};
  const int dplog[4] = {7, 7, 8, 8};
  const int Op[4]  = {128, 256, 256, 256};
  for (int l = 0; l < 4; ++l){
    int total = Op[l] << (dplog[l] + 2);
    pack_w<<<total/256, 256, 0, stream>>>(d_in[6 + l*5 + 0], d_in[6 + l*5 + 1],
                                          wt + wtoff[l], din[l], dou[l], dplog[l], flag);
  }

  // ---- CSR build ----
  hipMemsetAsync(cnt, 0, NSEG*sizeof(int), stream);
  counti_kernel<<<(EE+255)/256, 256, 0, stream>>>(ei, et, cnt);
  rcnt_kernel<<<(NSEG+255)/256, 256, 0, stream>>>(cnt, rcnt);
  int nb = (NSEG + 255)/256;
  scan1_kernel<<<nb, 256, 0, stream>>>(cnt, segoff, bsums);
  scan2_kernel<<<1, 256, 0, stream>>>(bsums, nb);
  scan3_kernel<<<nb, 256, 0, stream>>>(segoff, bsums);
  curinit_kernel<<<nb, 256, 0, stream>>>(segoff, cursor);
  place_kernel<<<(EE+255)/256, 256, 0, stream>>>(ei, et, cursor, srcs);
  // bsums is dead now -> becomes the 512B zero row for predicated gathers
  hipMemsetAsync(bsums, 0, 1024, stream);
  const bf_t* zrow = (const bf_t*)bsums;

  // ---- layer 0 input ----
  cvt_x<<<NN, 128, 0, stream>>>(x, Ab, flag);

  const int lda[4] = {512, 512, 1024, 1024};
  int aggBlocks = (NSEG + 3)/4;   // 4 waves per 256-block
  for (int l = 0; l < 4; ++l){
    int O = dou[l];
    if (DP[l] == 128)
      aggregate_wave<128><<<aggBlocks, 256, 0, stream>>>(Ab, lda[l], segoff, srcs, rcnt, zrow, Ab);
    else
      aggregate_wave<256><<<aggBlocks, 256, 0, stream>>>(Ab, lda[l], segoff, srcs, rcnt, zrow, Ab);

    hipMemsetAsync(sums, 0, 512*sizeof(float), stream);
    dim3 g2(391, Op[l]/128);
    gemm_mfma2<128><<<g2, 512, 0, stream>>>(Ab, lda[l], 4*DP[l], wt + wtoff[l], bfp[l],
                                            C, Op[l], O, sums);

    bn_finalize<<<1, 256, 0, stream>>>(sums, gf[l], bbf[l], scale, shift, O);

    int DPN = (l < 3) ? DP[l+1] : 256;
    int ldan = (l < 3) ? lda[l+1] : 1024;
    if (DPN == 128)
      bn_cvt<128><<<NN, 128, 0, stream>>>(C, Op[l], O, scale, shift, Ab, ldan);
    else
      bn_cvt<256><<<NN, 256, 0, stream>>>(C, Op[l], O, scale, shift, Ab, ldan);
  }

  hipMemsetAsync(pooled, 0, (size_t)GG*256*sizeof(float), stream);
  pool_kernel<<<dim3(GG, 8), 256, 0, stream>>>(Ab + 768, batch, pooled);
  final_kernel<<<GG, 128, 0, stream>>>(pooled, metaf, w1f, b1f, w2f, b2f_, d_out, flag);
}